// Round 12
// baseline (137.214 us; speedup 1.0000x reference)
//
#include <hip/hip_runtime.h>
#include <hip/hip_bf16.h>

typedef unsigned short u16;
typedef __attribute__((ext_vector_type(8))) short bf16x8;
typedef __attribute__((ext_vector_type(4))) float f32x4;
typedef __attribute__((ext_vector_type(4))) unsigned short u16x4;
typedef __attribute__((ext_vector_type(8))) unsigned short u16v8;

#define SQ 4096
#define HQ 128
#define NCHUNK 144   // per batch: sum over qt2 of ceil((qt2+1)/4), chunk = 8 key-tiles

__device__ __forceinline__ u16 f2b(float f) {
  unsigned int u = __float_as_uint(f);
  unsigned int r = (u + 0x7fffu + ((u >> 16) & 1u)) >> 16;  // RNE bf16
  return (u16)r;
}

__device__ __forceinline__ u16 f2b_fast(float f) {
  __hip_bfloat16 h = __float2bfloat16(f);
  return __builtin_bit_cast(u16, h);
}

__device__ __forceinline__ float b2f(u16 v) {
  unsigned int u = ((unsigned int)v) << 16;
  return __uint_as_float(u);
}

__device__ __forceinline__ void gload_lds16(const u16* gsrc, u16* ldst) {
  __builtin_amdgcn_global_load_lds((const __attribute__((address_space(1))) void*)gsrc,
                                   (__attribute__((address_space(3))) void*)ldst, 16, 0, 0);
}

// Wt[z][n][k] = W_z[k][n]  (bf16, B^T layout for MFMA B-frags)
__global__ __launch_bounds__(256) void k_wt(const float* __restrict__ Wq, const float* __restrict__ Wk,
                                            const float* __restrict__ Wv, u16* __restrict__ wt) {
  int idx = blockIdx.x * 256 + threadIdx.x;
  int z = idx >> 17, r = idx & 131071, n = r >> 10, k = r & 1023;
  const float* W = (z == 0) ? Wq : (z == 1) ? Wk : Wv;
  wt[idx] = f2b(W[k * 128 + n]);
}

// Fused conv+proj v5: block = 128 x-rows x 192 cols, grid (128,2) = 256 blocks,
// ALL co-resident at 2/CU (40 KB LDS). 512 thr (8 waves 2m x 4n), 12 MFMA per
// wave per iter. x f32 2-deep prefetch -> in-register cvt -> swizzled LDS;
// W via global_load_lds (pre-swizzled source), double-buffered.
__global__ __launch_bounds__(512, 4) void k_proj(const float* __restrict__ x, const u16* __restrict__ wt,
                                                 u16* __restrict__ qb, u16* __restrict__ kb,
                                                 u16* __restrict__ vt) {
  int mt = blockIdx.x, nh = blockIdx.y;
  int t = threadIdx.x;
  int w = t >> 6, lane = t & 63;
  int wm = w >> 2, wn = w & 3;
  int lr = lane & 15, lg = lane >> 4;

  __shared__ __align__(16) u16 xl[2][128 * 32];   // 2 x 8 KB
  __shared__ __align__(16) u16 wl[2][192 * 32];   // 2 x 12 KB

  int srow = t >> 2, g0 = t & 3;                   // x: row 0..127, 16B chunk 0..3
  const float* xg = x + (long)(mt * 128 + srow) * 1024 + g0 * 8;
  int xch = g0 ^ ((srow >> 1) & 3);                // swizzled 16B chunk
  int xoff = srow * 32 + xch * 8;                  // u16 offset within a buffer

  f32x4 acc[4][3];
#pragma unroll
  for (int i = 0; i < 4; ++i)
#pragma unroll
    for (int j = 0; j < 3; ++j) acc[i][j] = (f32x4){0.f, 0.f, 0.f, 0.f};

  const u16* wbase = wt + (long)(nh * 192) * 1024;

  // W stage: 768 16B-chunks, 512 threads -> 1.5/thread
  auto stage_w = [&](int bufi, int k0) {
#pragma unroll
    for (int i = 0; i < 2; ++i) {
      int ci = i * 512 + t;
      if (ci < 768) {
        int row = ci >> 2, ch = ci & 3;
        gload_lds16(wbase + (long)row * 1024 + k0 + ((ch ^ ((row >> 1) & 3)) << 3),
                    &wl[bufi][0] + ci * 8);
      }
    }
  };

  auto xwrite = [&](int bufi, float4 a, float4 b) {
    u16v8 o;
    o[0] = f2b_fast(a.x); o[1] = f2b_fast(a.y); o[2] = f2b_fast(a.z); o[3] = f2b_fast(a.w);
    o[4] = f2b_fast(b.x); o[5] = f2b_fast(b.y); o[6] = f2b_fast(b.z); o[7] = f2b_fast(b.w);
    *(u16v8*)(&xl[bufi][0] + xoff) = o;
  };

  // prologue: ks=0 staged; ks=1 data in flight
  {
    float4 a0 = *(const float4*)(xg);
    float4 a1 = *(const float4*)(xg + 4);
    stage_w(0, 0);
    xwrite(0, a0, a1);
  }
  float4 p0a = *(const float4*)(xg + 32);
  float4 p0b = *(const float4*)(xg + 36);
  __syncthreads();

  for (int ks = 0; ks < 32; ++ks) {
    int cur = ks & 1;
    float4 p1a, p1b;
    if (ks + 2 < 32) {                      // 2-deep issue
      p1a = *(const float4*)(xg + (ks + 2) * 32);
      p1b = *(const float4*)(xg + (ks + 2) * 32 + 4);
    }
    if (ks + 1 < 32) {
      stage_w(cur ^ 1, (ks + 1) * 32);
      xwrite(cur ^ 1, p0a, p0b);
    }
    bf16x8 af[4], bfr[3];
#pragma unroll
    for (int i = 0; i < 4; ++i) {
      int row = wm * 64 + i * 16 + lr;
      af[i] = *(const bf16x8*)(&xl[cur][0] + row * 32 + ((lg ^ ((row >> 1) & 3)) << 3));
    }
#pragma unroll
    for (int j = 0; j < 3; ++j) {
      int row = wn * 48 + j * 16 + lr;
      bfr[j] = *(const bf16x8*)(&wl[cur][0] + row * 32 + ((lg ^ ((row >> 1) & 3)) << 3));
    }
#pragma unroll
    for (int i = 0; i < 4; ++i)
#pragma unroll
      for (int j = 0; j < 3; ++j)
        acc[i][j] = __builtin_amdgcn_mfma_f32_16x16x32_bf16(af[i], bfr[j], acc[i][j], 0, 0, 0);
    p0a = p1a; p0b = p1b;
    __syncthreads();
  }

  // epilogue: C layout row=(lane>>4)*4+reg, col=lane&15
#pragma unroll
  for (int i = 0; i < 4; ++i)
#pragma unroll
    for (int j = 0; j < 3; ++j)
#pragma unroll
      for (int r = 0; r < 4; ++r) {
        int m = mt * 128 + wm * 64 + i * 16 + lg * 4 + r;
        int col = nh * 192 + wn * 48 + j * 16 + lr;
        int z = col >> 7, cz = col & 127;
        u16 v = f2b(acc[i][j][r]);
        if (z == 0) qb[(long)m * 128 + cz] = v;
        else if (z == 1) kb[(long)m * 128 + cz] = v;
        else { int bb = m >> 12, sR = m & 4095; vt[(long)bb * 524288 + (long)cz * 4096 + sR] = v; }
      }
}

// flash attention v8: v6 core, SINGLE-buffered K/V (48 KB LDS -> 3 blocks/CU,
// whole 576-block grid co-resident; TLP covers stage latency; 2 barriers/iter).
// Uniform split-K chunks (8 key-tiles), fixed-max softmax, ones-MFMA row-sum,
// bf16 partials.
__global__ __launch_bounds__(512) void k_attn(const u16* __restrict__ qb, const u16* __restrict__ kb,
                                              const u16* __restrict__ vt, const int* __restrict__ kmask,
                                              u16* __restrict__ po, float* __restrict__ pl) {
  const float SCALE_LOG2 = 0.08838834764831845f * 1.4426950408889634f;
  const float MFIX = 24.0f;
  int f = (NCHUNK - 1) - (int)blockIdx.x;
  int b = blockIdx.y;
  // decode f -> (qt2, kc): nch(q) = ceil((q+1)/4) = (q+4)>>2
  int qt2 = 0, cum = 0;
  while (cum + ((qt2 + 4) >> 2) <= f) { cum += (qt2 + 4) >> 2; ++qt2; }
  int kc = f - cum;
  int ntile = 2 * qt2 + 2;
  int kt0 = kc * 8;
  int kt1 = min(kt0 + 8, ntile);

  int t = threadIdx.x, w = t >> 6, lane = t & 63;
  int lr = lane & 15, lg = lane >> 4, sw = lr & 7;
  int qrow0 = qt2 * 128 + w * 16;
  const u16* Q = qb + ((long)(b * SQ + qrow0)) * HQ;
  const u16* K = kb + (long)b * SQ * HQ;
  const u16* V = vt + (long)b * HQ * SQ;   // V^T: [128][SQ]
  const int* msk = kmask + b * SQ;

  __shared__ __align__(16) u16 Kl[64 * 128];      // 16 KB
  __shared__ __align__(16) u16 Vl[128 * 64];      // 16 KB
  __shared__ __align__(16) u16 plds[8][16 * 64];  // 16 KB, XOR-chunk layout

  bf16x8 aq[4];
#pragma unroll
  for (int c = 0; c < 4; ++c) aq[c] = *(const bf16x8*)(Q + lr * HQ + c * 32 + lg * 8);

  bf16x8 ones;
#pragma unroll
  for (int e = 0; e < 8; ++e) ones[e] = (short)0x3F80;

  f32x4 o[8];
#pragma unroll
  for (int n = 0; n < 8; ++n) o[n] = (f32x4){0.f, 0.f, 0.f, 0.f};
  f32x4 l_acc = (f32x4){0.f, 0.f, 0.f, 0.f};

  auto stage = [&](int kb0) {
    const u16* Kg = K + (long)kb0 * HQ;
    const u16* Vg = V + kb0;
#pragma unroll
    for (int i = 0; i < 2; ++i) {
      int ci = w * 2 + i;
      int o16 = ci * 64 + lane;
      int row = o16 >> 4, ch = o16 & 15;
      gload_lds16(Kg + row * HQ + ((ch ^ (row & 7)) << 3), &Kl[ci * 512]);
    }
#pragma unroll
    for (int i = 0; i < 2; ++i) {
      int ci = w * 2 + i;
      int o16 = ci * 64 + lane;
      int row = o16 >> 3, ch = o16 & 7;
      gload_lds16(Vg + (long)row * SQ + ((ch ^ (row & 7)) << 3), &Vl[ci * 512]);
    }
  };

  u16* pw = &plds[w][0];
  for (int kt = kt0; kt < kt1; ++kt) {
    int kb0 = kt * 64;
    stage(kb0);
    __syncthreads();                       // stage drained for all waves

    if (kb0 <= qrow0 + 15) {               // wave-uniform: any valid keys?
      f32x4 s[4];
#pragma unroll
      for (int h = 0; h < 4; ++h) {
        f32x4 acc = (f32x4){0.f, 0.f, 0.f, 0.f};
        const u16* Kp = &Kl[(h * 16 + lr) * 128];
#pragma unroll
        for (int c = 0; c < 4; ++c) {
          bf16x8 bk = *(const bf16x8*)(Kp + (((c * 4 + lg) ^ sw) << 3));
          acc = __builtin_amdgcn_mfma_f32_16x16x32_bf16(aq[c], bk, acc, 0, 0, 0);
        }
        s[h] = acc;
      }
      float mf[4];
#pragma unroll
      for (int h = 0; h < 4; ++h) mf[h] = (msk[kb0 + h * 16 + lr] != 0) ? 1.0f : 0.0f;
      bool needc = (kb0 + 63 > qrow0);
#pragma unroll
      for (int r = 0; r < 4; ++r) {
        int row = lg * 4 + r;
        int qr = qrow0 + row;
#pragma unroll
        for (int h = 0; h < 4; ++h) {
          float p = __builtin_exp2f(fmaf(s[h][r], SCALE_LOG2, -MFIX)) * mf[h];
          if (needc) p = ((kb0 + h * 16 + lr) <= qr) ? p : 0.0f;
          int poff = row * 64 + ((((h * 2 + (lr >> 3)) ^ (row & 7))) << 3) + (lr & 7);
          pw[poff] = f2b_fast(p);
        }
      }
      bf16x8 ap0 = *(const bf16x8*)(pw + lr * 64 + ((lg ^ sw) << 3));
      bf16x8 ap1 = *(const bf16x8*)(pw + lr * 64 + (((4 + lg) ^ sw) << 3));
      l_acc = __builtin_amdgcn_mfma_f32_16x16x32_bf16(ap0, ones, l_acc, 0, 0, 0);
      l_acc = __builtin_amdgcn_mfma_f32_16x16x32_bf16(ap1, ones, l_acc, 0, 0, 0);
#pragma unroll
      for (int n = 0; n < 8; ++n) {
        const u16* Vp = &Vl[(n * 16 + lr) * 64];
        bf16x8 bv0 = *(const bf16x8*)(Vp + ((lg ^ sw) << 3));
        bf16x8 bv1 = *(const bf16x8*)(Vp + (((4 + lg) ^ sw) << 3));
        o[n] = __builtin_amdgcn_mfma_f32_16x16x32_bf16(ap0, bv0, o[n], 0, 0, 0);
        o[n] = __builtin_amdgcn_mfma_f32_16x16x32_bf16(ap1, bv1, o[n], 0, 0, 0);
      }
    }
    __syncthreads();                       // all waves done before next overwrite
  }

  // ---- write partials (bf16 O, f32 l)
  long p = (long)b * NCHUNK + f;
  u16* pob = po + p * 16384;  // [128][128] bf16
#pragma unroll
  for (int n = 0; n < 8; ++n)
#pragma unroll
    for (int r = 0; r < 4; ++r)
      pob[(w * 16 + lg * 4 + r) * 128 + n * 16 + lr] = f2b_fast(o[n][r]);
  if (lr == 0) {
#pragma unroll
    for (int r = 0; r < 4; ++r) pl[p * 128 + w * 16 + lg * 4 + r] = l_acc[r];
  }
}

// merge: out[b, qt2*128+row, :] = sum_i po[i] / sum_i pl[i]
__global__ __launch_bounds__(256) void k_merge(const u16* __restrict__ po, const float* __restrict__ pl,
                                               float* __restrict__ out) {
  int qt2 = blockIdx.x, b = blockIdx.y;
  int nch = (qt2 + 4) >> 2;
  int pre = 0;
  for (int q = 0; q < qt2; ++q) pre += (q + 4) >> 2;
  long pbase = (long)b * NCHUNK + pre;
  int t = threadIdx.x;
  int row = t >> 1, c0 = (t & 1) * 64;
  float l = 0.f;
  for (int i = 0; i < nch; ++i) l += pl[(pbase + i) * 128 + row];
  float inv = 1.0f / l;
  const u16* p0 = po + pbase * 16384 + row * 128 + c0;
  float* orow = out + ((long)(b * SQ + qt2 * 128 + row)) * HQ + c0;
#pragma unroll
  for (int j = 0; j < 64; j += 4) {
    float acc0 = 0.f, acc1 = 0.f, acc2 = 0.f, acc3 = 0.f;
    for (int i = 0; i < nch; ++i) {
      u16x4 v = *(const u16x4*)(p0 + (long)i * 16384 + j);
      acc0 += b2f(v[0]); acc1 += b2f(v[1]); acc2 += b2f(v[2]); acc3 += b2f(v[3]);
    }
    float4 r = {acc0 * inv, acc1 * inv, acc2 * inv, acc3 * inv};
    *(float4*)(orow + j) = r;
  }
}

extern "C" void kernel_launch(void* const* d_in, const int* in_sizes, int n_in,
                              void* d_out, int out_size, void* d_ws, size_t ws_size,
                              hipStream_t stream) {
  const float* x  = (const float*)d_in[0];
  const float* Wq = (const float*)d_in[1];
  const float* Wk = (const float*)d_in[2];
  const float* Wv = (const float*)d_in[3];
  const int* kmask = (const int*)d_in[4];
  char* ws = (char*)d_ws;
  u16* wt = (u16*)(ws + 33554432);            // 768 KB: Wt (dead after k_proj)
  u16* qb = (u16*)(ws + 34340864);            // 4 MB: Q bf16
  u16* kb = (u16*)(ws + 38535168);            // 4 MB: K bf16
  u16* vt = (u16*)(ws + 42729472);            // 4 MB: V^T bf16 [4][128][4096]
  u16* po = (u16*)ws;                         // 18.9 MB partial O (bf16)
  float* pl = (float*)(ws + 31195136);        // 295 KB partial l (po-region tail)
  float* out = (float*)d_out;

  k_wt<<<1536, 256, 0, stream>>>(Wq, Wk, Wv, wt);
  k_proj<<<dim3(128, 2), 512, 0, stream>>>(x, wt, qb, kb, vt);
  k_attn<<<dim3(NCHUNK, 4), 512, 0, stream>>>(qb, kb, vt, kmask, po, pl);
  k_merge<<<dim3(32, 4), 256, 0, stream>>>(po, pl, out);
}

// Round 13
// 125.700 us; speedup vs baseline: 1.0916x; 1.0916x over previous
//
#include <hip/hip_runtime.h>
#include <hip/hip_bf16.h>

typedef unsigned short u16;
typedef __attribute__((ext_vector_type(8))) short bf16x8;
typedef __attribute__((ext_vector_type(4))) float f32x4;
typedef __attribute__((ext_vector_type(4))) unsigned short u16x4;

#define SQ 4096
#define HQ 128
#define NCHUNK 144   // per batch: sum over qt2 of ceil((qt2+1)/4), chunk = 8 key-tiles

__device__ __forceinline__ u16 f2b(float f) {
  unsigned int u = __float_as_uint(f);
  unsigned int r = (u + 0x7fffu + ((u >> 16) & 1u)) >> 16;  // RNE bf16
  return (u16)r;
}

__device__ __forceinline__ u16 f2b_fast(float f) {
  __hip_bfloat16 h = __float2bfloat16(f);
  return __builtin_bit_cast(u16, h);
}

__device__ __forceinline__ float b2f(u16 v) {
  unsigned int u = ((unsigned int)v) << 16;
  return __uint_as_float(u);
}

__device__ __forceinline__ void gload_lds16(const void* gsrc, void* ldst) {
  __builtin_amdgcn_global_load_lds((const __attribute__((address_space(1))) void*)gsrc,
                                   (__attribute__((address_space(3))) void*)ldst, 16, 0, 0);
}

// Wt[z][n][k] = W_z[k][n]  (bf16, B^T layout for MFMA B-frags)
__global__ __launch_bounds__(256) void k_wt(const float* __restrict__ Wq, const float* __restrict__ Wk,
                                            const float* __restrict__ Wv, u16* __restrict__ wt) {
  int idx = blockIdx.x * 256 + threadIdx.x;
  int z = idx >> 17, r = idx & 131071, n = r >> 10, k = r & 1023;
  const float* W = (z == 0) ? Wq : (z == 1) ? Wk : Wv;
  wt[idx] = f2b(W[k * 128 + n]);
}

// Fused conv+proj v6 (m97-style): tile 128 rows x 96 cols, grid (128,4) = 512
// blocks, 256 thr (4 waves 2m x 2n, 12 MFMA/wave/iter). A staged AS F32 via
// global_load_lds (async, no reg round-trip), converted to bf16 at frag-load;
// B (Wt) staged bf16 via global_load_lds. Both double-buffered, 1 barrier/iter.
// A-swizzle ch^(row&7) over 8 f32-chunks/row; B-swizzle ch^((row>>1)&3).
__global__ __launch_bounds__(256) void k_proj(const float* __restrict__ x, const u16* __restrict__ wt,
                                              u16* __restrict__ qb, u16* __restrict__ kb,
                                              u16* __restrict__ vt) {
  int mt = blockIdx.x, nh = blockIdx.y;
  int t = threadIdx.x;
  int w = t >> 6, lane = t & 63;
  int wm = w >> 1, wn = w & 1;
  int lr = lane & 15, lg = lane >> 4;

  __shared__ __align__(16) float Al[2][128 * 32];  // 2 x 16 KB (f32)
  __shared__ __align__(16) u16 Bl[2][96 * 32];     // 2 x 6 KB (bf16)

  f32x4 acc[4][3];
#pragma unroll
  for (int i = 0; i < 4; ++i)
#pragma unroll
    for (int j = 0; j < 3; ++j) acc[i][j] = (f32x4){0.f, 0.f, 0.f, 0.f};

  const float* xbase = x + (long)(mt * 128) * 1024;
  const u16* wbase = wt + (long)(nh * 96) * 1024;

  // A stage: 1024 16B chunks (128 rows x 8 chunks), 4/thread
  auto stage_a = [&](int bufi, int k0) {
#pragma unroll
    for (int i = 0; i < 4; ++i) {
      int ci = i * 256 + t;
      int row = ci >> 3, ch = ci & 7;
      gload_lds16(xbase + (long)row * 1024 + k0 + ((ch ^ (row & 7)) << 2),
                  &Al[bufi][0] + ci * 4);
    }
  };
  // B stage: 384 16B chunks (96 rows x 4 chunks), 1.5/thread
  auto stage_b = [&](int bufi, int k0) {
    {
      int ci = t;
      int row = ci >> 2, ch = ci & 3;
      gload_lds16(wbase + (long)row * 1024 + k0 + ((ch ^ ((row >> 1) & 3)) << 3),
                  &Bl[bufi][0] + ci * 8);
    }
    if (t < 128) {
      int ci = 256 + t;
      int row = ci >> 2, ch = ci & 3;
      gload_lds16(wbase + (long)row * 1024 + k0 + ((ch ^ ((row >> 1) & 3)) << 3),
                  &Bl[bufi][0] + ci * 8);
    }
  };

  stage_a(0, 0);
  stage_b(0, 0);
  __syncthreads();

  for (int ks = 0; ks < 32; ++ks) {
    int cur = ks & 1;
    if (ks + 1 < 32) {                       // prefetch next K-step (async)
      stage_a(cur ^ 1, (ks + 1) * 32);
      stage_b(cur ^ 1, (ks + 1) * 32);
    }
    bf16x8 af[4], bfr[3];
#pragma unroll
    for (int i = 0; i < 4; ++i) {
      int row = wm * 64 + i * 16 + lr;
      const float* Ap = &Al[cur][row * 32];
      int sz = row & 7;
      float4 fa = *(const float4*)(Ap + (((2 * lg) ^ sz) << 2));
      float4 fb = *(const float4*)(Ap + (((2 * lg + 1) ^ sz) << 2));
      bf16x8 v;
      v[0] = (short)f2b_fast(fa.x); v[1] = (short)f2b_fast(fa.y);
      v[2] = (short)f2b_fast(fa.z); v[3] = (short)f2b_fast(fa.w);
      v[4] = (short)f2b_fast(fb.x); v[5] = (short)f2b_fast(fb.y);
      v[6] = (short)f2b_fast(fb.z); v[7] = (short)f2b_fast(fb.w);
      af[i] = v;
    }
#pragma unroll
    for (int j = 0; j < 3; ++j) {
      int row = wn * 48 + j * 16 + lr;
      bfr[j] = *(const bf16x8*)(&Bl[cur][0] + row * 32 + ((lg ^ ((row >> 1) & 3)) << 3));
    }
#pragma unroll
    for (int i = 0; i < 4; ++i)
#pragma unroll
      for (int j = 0; j < 3; ++j)
        acc[i][j] = __builtin_amdgcn_mfma_f32_16x16x32_bf16(af[i], bfr[j], acc[i][j], 0, 0, 0);
    __syncthreads();                         // drains prefetch + gates buffer swap
  }

  // epilogue: C layout row=(lane>>4)*4+reg, col=lane&15
#pragma unroll
  for (int i = 0; i < 4; ++i)
#pragma unroll
    for (int j = 0; j < 3; ++j)
#pragma unroll
      for (int r = 0; r < 4; ++r) {
        int m = mt * 128 + wm * 64 + i * 16 + lg * 4 + r;
        int col = nh * 96 + wn * 48 + j * 16 + lr;
        int z = col >> 7, cz = col & 127;
        u16 v = f2b(acc[i][j][r]);
        if (z == 0) qb[(long)m * 128 + cz] = v;
        else if (z == 1) kb[(long)m * 128 + cz] = v;
        else { int bb = m >> 12, sR = m & 4095; vt[(long)bb * 524288 + (long)cz * 4096 + sR] = v; }
      }
}

// flash attention v6 (R11 exact, best measured 54us): uniform split-K chunks
// (8 key-tiles each); 576 blocks. 8-wave blocks share K/V staging, QBLK=128,
// KVBLK=64, double-buffered, fixed-max softmax, ones-MFMA row-sum, bf16 partials.
__global__ __launch_bounds__(512, 4) void k_attn(const u16* __restrict__ qb, const u16* __restrict__ kb,
                                                 const u16* __restrict__ vt, const int* __restrict__ kmask,
                                                 u16* __restrict__ po, float* __restrict__ pl) {
  const float SCALE_LOG2 = 0.08838834764831845f * 1.4426950408889634f;
  const float MFIX = 24.0f;
  int f = (NCHUNK - 1) - (int)blockIdx.x;  // long chunks (big qt2) first
  int b = blockIdx.y;
  // decode f -> (qt2, kc): nch(q) = ceil((q+1)/4) = (q+4)>>2
  int qt2 = 0, cum = 0;
  while (cum + ((qt2 + 4) >> 2) <= f) { cum += (qt2 + 4) >> 2; ++qt2; }
  int kc = f - cum;
  int ntile = 2 * qt2 + 2;
  int kt0 = kc * 8;
  int kt1 = min(kt0 + 8, ntile);

  int t = threadIdx.x, w = t >> 6, lane = t & 63;
  int lr = lane & 15, lg = lane >> 4, sw = lr & 7;
  int qrow0 = qt2 * 128 + w * 16;
  const u16* Q = qb + ((long)(b * SQ + qrow0)) * HQ;
  const u16* K = kb + (long)b * SQ * HQ;
  const u16* V = vt + (long)b * HQ * SQ;   // V^T: [128][SQ]
  const int* msk = kmask + b * SQ;

  __shared__ __align__(16) u16 Kl[2][64 * 128];   // 2 x 16 KB
  __shared__ __align__(16) u16 Vl[2][128 * 64];   // 2 x 16 KB
  __shared__ __align__(16) u16 plds[8][16 * 64];  // 16 KB, XOR-chunk layout

  bf16x8 aq[4];
#pragma unroll
  for (int c = 0; c < 4; ++c) aq[c] = *(const bf16x8*)(Q + lr * HQ + c * 32 + lg * 8);

  bf16x8 ones;
#pragma unroll
  for (int e = 0; e < 8; ++e) ones[e] = (short)0x3F80;

  f32x4 o[8];
#pragma unroll
  for (int n = 0; n < 8; ++n) o[n] = (f32x4){0.f, 0.f, 0.f, 0.f};
  f32x4 l_acc = (f32x4){0.f, 0.f, 0.f, 0.f};

  auto stage = [&](int bufi, int kb0) {
    const u16* Kg = K + (long)kb0 * HQ;
    const u16* Vg = V + kb0;
#pragma unroll
    for (int i = 0; i < 2; ++i) {
      int ci = w * 2 + i;
      int o16 = ci * 64 + lane;
      int row = o16 >> 4, ch = o16 & 15;
      gload_lds16(Kg + row * HQ + ((ch ^ (row & 7)) << 3), &Kl[bufi][ci * 512]);
    }
#pragma unroll
    for (int i = 0; i < 2; ++i) {
      int ci = w * 2 + i;
      int o16 = ci * 64 + lane;
      int row = o16 >> 3, ch = o16 & 7;
      gload_lds16(Vg + (long)row * SQ + ((ch ^ (row & 7)) << 3), &Vl[bufi][ci * 512]);
    }
  };

  stage(0, kt0 * 64);
  __syncthreads();

  u16* pw = &plds[w][0];
  for (int kt = kt0; kt < kt1; ++kt) {
    int cur = (kt - kt0) & 1;
    int kb0 = kt * 64;
    if (kt + 1 < kt1) stage(cur ^ 1, kb0 + 64);

    if (kb0 <= qrow0 + 15) {                 // wave-uniform: any valid keys?
      f32x4 s[4];
#pragma unroll
      for (int h = 0; h < 4; ++h) {
        f32x4 acc = (f32x4){0.f, 0.f, 0.f, 0.f};
        const u16* Kp = &Kl[cur][(h * 16 + lr) * 128];
#pragma unroll
        for (int c = 0; c < 4; ++c) {
          bf16x8 bk = *(const bf16x8*)(Kp + (((c * 4 + lg) ^ sw) << 3));
          acc = __builtin_amdgcn_mfma_f32_16x16x32_bf16(aq[c], bk, acc, 0, 0, 0);
        }
        s[h] = acc;
      }
      float mf[4];
#pragma unroll
      for (int h = 0; h < 4; ++h) mf[h] = (msk[kb0 + h * 16 + lr] != 0) ? 1.0f : 0.0f;
      bool needc = (kb0 + 63 > qrow0);       // tile crosses diagonal for this wave
#pragma unroll
      for (int r = 0; r < 4; ++r) {
        int row = lg * 4 + r;
        int qr = qrow0 + row;
#pragma unroll
        for (int h = 0; h < 4; ++h) {
          float p = __builtin_exp2f(fmaf(s[h][r], SCALE_LOG2, -MFIX)) * mf[h];
          if (needc) p = ((kb0 + h * 16 + lr) <= qr) ? p : 0.0f;
          int poff = row * 64 + ((((h * 2 + (lr >> 3)) ^ (row & 7))) << 3) + (lr & 7);
          pw[poff] = f2b_fast(p);
        }
      }
      bf16x8 ap0 = *(const bf16x8*)(pw + lr * 64 + ((lg ^ sw) << 3));
      bf16x8 ap1 = *(const bf16x8*)(pw + lr * 64 + (((4 + lg) ^ sw) << 3));
      l_acc = __builtin_amdgcn_mfma_f32_16x16x32_bf16(ap0, ones, l_acc, 0, 0, 0);
      l_acc = __builtin_amdgcn_mfma_f32_16x16x32_bf16(ap1, ones, l_acc, 0, 0, 0);
#pragma unroll
      for (int n = 0; n < 8; ++n) {
        const u16* Vp = &Vl[cur][(n * 16 + lr) * 64];
        bf16x8 bv0 = *(const bf16x8*)(Vp + ((lg ^ sw) << 3));
        bf16x8 bv1 = *(const bf16x8*)(Vp + (((4 + lg) ^ sw) << 3));
        o[n] = __builtin_amdgcn_mfma_f32_16x16x32_bf16(ap0, bv0, o[n], 0, 0, 0);
        o[n] = __builtin_amdgcn_mfma_f32_16x16x32_bf16(ap1, bv1, o[n], 0, 0, 0);
      }
    }
    __syncthreads();
  }

  // ---- write partials (bf16 O, f32 l)
  long p = (long)b * NCHUNK + f;
  u16* pob = po + p * 16384;  // [128][128] bf16
#pragma unroll
  for (int n = 0; n < 8; ++n)
#pragma unroll
    for (int r = 0; r < 4; ++r)
      pob[(w * 16 + lg * 4 + r) * 128 + n * 16 + lr] = f2b_fast(o[n][r]);
  if (lr == 0) {
#pragma unroll
    for (int r = 0; r < 4; ++r) pl[p * 128 + w * 16 + lg * 4 + r] = l_acc[r];
  }
}

// merge: out[b, qt2*128+row, :] = sum_i po[i] / sum_i pl[i]
__global__ __launch_bounds__(256) void k_merge(const u16* __restrict__ po, const float* __restrict__ pl,
                                               float* __restrict__ out) {
  int qt2 = blockIdx.x, b = blockIdx.y;
  int nch = (qt2 + 4) >> 2;
  int pre = 0;
  for (int q = 0; q < qt2; ++q) pre += (q + 4) >> 2;
  long pbase = (long)b * NCHUNK + pre;
  int t = threadIdx.x;
  int row = t >> 1, c0 = (t & 1) * 64;
  float l = 0.f;
  for (int i = 0; i < nch; ++i) l += pl[(pbase + i) * 128 + row];
  float inv = 1.0f / l;
  const u16* p0 = po + pbase * 16384 + row * 128 + c0;
  float* orow = out + ((long)(b * SQ + qt2 * 128 + row)) * HQ + c0;
#pragma unroll
  for (int j = 0; j < 64; j += 4) {
    float acc0 = 0.f, acc1 = 0.f, acc2 = 0.f, acc3 = 0.f;
    for (int i = 0; i < nch; ++i) {
      u16x4 v = *(const u16x4*)(p0 + (long)i * 16384 + j);
      acc0 += b2f(v[0]); acc1 += b2f(v[1]); acc2 += b2f(v[2]); acc3 += b2f(v[3]);
    }
    float4 r = {acc0 * inv, acc1 * inv, acc2 * inv, acc3 * inv};
    *(float4*)(orow + j) = r;
  }
}

extern "C" void kernel_launch(void* const* d_in, const int* in_sizes, int n_in,
                              void* d_out, int out_size, void* d_ws, size_t ws_size,
                              hipStream_t stream) {
  const float* x  = (const float*)d_in[0];
  const float* Wq = (const float*)d_in[1];
  const float* Wk = (const float*)d_in[2];
  const float* Wv = (const float*)d_in[3];
  const int* kmask = (const int*)d_in[4];
  char* ws = (char*)d_ws;
  u16* wt = (u16*)(ws + 33554432);            // 768 KB: Wt (dead after k_proj)
  u16* qb = (u16*)(ws + 34340864);            // 4 MB: Q bf16
  u16* kb = (u16*)(ws + 38535168);            // 4 MB: K bf16
  u16* vt = (u16*)(ws + 42729472);            // 4 MB: V^T bf16 [4][128][4096]
  u16* po = (u16*)ws;                         // 18.9 MB partial O (bf16)
  float* pl = (float*)(ws + 31195136);        // 295 KB partial l (po-region tail)
  float* out = (float*)d_out;

  k_wt<<<1536, 256, 0, stream>>>(Wq, Wk, Wv, wt);
  k_proj<<<dim3(128, 4), 256, 0, stream>>>(x, wt, qb, kb, vt);
  k_attn<<<dim3(NCHUNK, 4), 512, 0, stream>>>(qb, kb, vt, kmask, po, pl);
  k_merge<<<dim3(32, 4), 256, 0, stream>>>(po, pl, out);
}